// Round 10
// baseline (665.808 us; speedup 1.0000x reference)
//
#include <hip/hip_runtime.h>
#include <math.h>

#define NG 6
#define KD 40
#define CB 1024
#define NB 32
#define TP 2000
#define RPB 128              // rows per block (4 waves x 32)
#define THREADS 256
#define NBLK 500             // 64000 / 128
#define ZN 480000
#define ZG 80000
#define EPS_D 0.02f
#define PK_G 98304           // shorts per group in Epack (32 tiles * 3072)
#define PK_T 3072            // shorts per tile (hi 1536 + lo 1536)
#define PK_P 1536            // shorts per part

typedef __attribute__((ext_vector_type(8))) short bf16x8;
typedef __attribute__((ext_vector_type(16))) float f32x16;

__device__ __forceinline__ unsigned short bf16rne(float v) {
  unsigned u = __float_as_uint(v);
  return (unsigned short)((u + 0x7FFFu + ((u >> 16) & 1u)) >> 16);
}
__device__ __forceinline__ float bf16val(unsigned short h) {
  return __uint_as_float(((unsigned)h) << 16);
}
__device__ __forceinline__ void bf16split(float v, unsigned short& h, unsigned short& l) {
  h = bf16rne(v);
  l = bf16rne(v - bf16val(h));   // hi residual is exact, lo captures it
}
__device__ __forceinline__ bf16x8 ldfrag16(const unsigned short* p) {
  union { uint4 q; bf16x8 v; } u;
  u.q = *(const uint4*)p;
  return u.v;
}

// ---- prep: et[g][c][k] fp32 contiguous; np-exact ||e||^2; fragment-ordered bf16 pack
__global__ void prep_kernel(const float* __restrict__ emb, float* __restrict__ et,
                            float* __restrict__ e2, unsigned short* __restrict__ epack) {
  int c = blockIdx.x * blockDim.x + threadIdx.x;
  int g = blockIdx.y;
  if (c >= CB) return;
  const float* eg = emb + (size_t)g * KD * CB;
  float ev[KD];
  float* o = et + ((size_t)g * CB + c) * KD;
  float s = 0.f;
#pragma unroll
  for (int k = 0; k < KD; ++k) {
    float v = eg[k * CB + c];
    ev[k] = v;
    o[k] = v;
    s = __fadd_rn(s, __fmul_rn(v, v));   // np-exact serial unfused
  }
  e2[g * CB + c] = s;

  // 3-way bf16 split of the 0.5*||e||^2 seed
  float sv = 0.5f * s;
  unsigned short p0 = bf16rne(sv);
  float v1 = sv - bf16val(p0);
  unsigned short p1 = bf16rne(v1);
  unsigned short p2 = bf16rne(v1 - bf16val(p1));

  int tile = c >> 5, j32 = c & 31;
  unsigned short* tb = epack + (size_t)g * PK_G + (size_t)tile * PK_T;
#pragma unroll
  for (int s2 = 0; s2 < 3; ++s2)
#pragma unroll
    for (int gg = 0; gg < 2; ++gg) {
      union { uint4 q; unsigned short sh[8]; } uh, ul;
#pragma unroll
      for (int j = 0; j < 8; ++j) {
        int k = s2 * 16 + gg * 8 + j;
        if (k < KD) {
          bf16split(ev[k], uh.sh[j], ul.sh[j]);
        } else {
          uh.sh[j] = (k == 40) ? p0 : (k == 41) ? p1 : (k == 42) ? p2 : (unsigned short)0;
          ul.sh[j] = 0;
        }
      }
      unsigned short* ph = tb + ((size_t)(s2 * 2 + gg) * 32 + j32) * 8;
      *(uint4*)ph = uh.q;
      *(uint4*)(ph + PK_P) = ul.q;
    }
}

__global__ __launch_bounds__(THREADS, 4) void vq_kernel(
    const float* __restrict__ z, const float* __restrict__ et,
    const float* __restrict__ e2, const unsigned short* __restrict__ epack,
    float* __restrict__ out, float* __restrict__ partials) {
  const int g = blockIdx.y;
  const int bb = blockIdx.x;
  const int tid = threadIdx.x;
  const int lane = tid & 63;
  const int gg = lane >> 5;
  const int j32 = lane & 31;
  const int rowloc = (tid >> 6) * 32 + j32;
  const int rid = bb * RPB + rowloc;
  const int n = rid / TP;
  const int tt = rid - n * TP;

  const float* etg = et + (size_t)g * CB * KD;
  const float* e2g = e2 + g * CB;

  __shared__ float r0s[THREADS], r1s[THREADS];

  // ---- row x in registers; x2np (numpy pairwise-8, verified r6)
  const float* zp = z + (size_t)n * ZN + (size_t)g * ZG + tt;
  float x[KD];
#pragma unroll
  for (int k = 0; k < KD; ++k) x[k] = zp[(size_t)k * TP];
  float x2np;
  {
    float r[8];
#pragma unroll
    for (int j = 0; j < 8; ++j) r[j] = __fmul_rn(x[j], x[j]);
#pragma unroll
    for (int i = 8; i < KD; i += 8)
#pragma unroll
      for (int j = 0; j < 8; ++j)
        r[j] = __fadd_rn(r[j], __fmul_rn(x[i + j], x[i + j]));
    x2np = __fadd_rn(__fadd_rn(__fadd_rn(r[0], r[1]), __fadd_rn(r[2], r[3])),
                     __fadd_rn(__fadd_rn(r[4], r[5]), __fadd_rn(r[6], r[7])));
  }

  // ---- B fragments from -x, static per-gg k-slices (verified r9)
  bf16x8 xh[3], xl[3];
#define PACK8(DH, DL, B0) { \
    union { unsigned short s[8]; bf16x8 v; } uh, ul; \
    _Pragma("unroll") \
    for (int j = 0; j < 8; ++j) { \
      unsigned short h, l; bf16split(-x[(B0) + j], h, l); \
      uh.s[j] = h; ul.s[j] = l; } \
    DH = uh.v; DL = ul.v; }
  if (gg == 0) {
    PACK8(xh[0], xl[0], 0)
    PACK8(xh[1], xl[1], 16)
    PACK8(xh[2], xl[2], 32)
  } else {
    PACK8(xh[0], xl[0], 8)
    PACK8(xh[1], xl[1], 24)
    union { unsigned short s[8]; bf16x8 v; } uh;
#pragma unroll
    for (int j = 0; j < 8; ++j) uh.s[j] = (j < 3) ? (unsigned short)0x3F80 : (unsigned short)0;
    xh[2] = uh.v;
    union { unsigned short s[8]; bf16x8 v; } uz;
#pragma unroll
    for (int j = 0; j < 8; ++j) uz.s[j] = 0;
    xl[2] = uz.v;
  }
#undef PACK8

  f32x16 zacc;
#pragma unroll
  for (int i = 0; i < 16; ++i) zacc[i] = 0.f;

  // per-lane fragment base: frag offset = ((s2*2+gg)*32 + j32)*8 shorts
  const unsigned short* lanep = epack + (size_t)g * PK_G + gg * 256 + j32 * 8;

  float thr = INFINITY;   // sc < thr  <=>  2*sc + x2np < best_d + EPS
  float best_d = INFINITY;
  int best_i = CB;

#pragma unroll 2
  for (int tile = 0; tile < 32; ++tile) {
    const unsigned short* tb = lanep + (size_t)tile * PK_T;
    bf16x8 eh0 = ldfrag16(tb);
    bf16x8 eh1 = ldfrag16(tb + 512);
    bf16x8 eh2 = ldfrag16(tb + 1024);
    bf16x8 el0 = ldfrag16(tb + 1536);
    bf16x8 el1 = ldfrag16(tb + 2048);
    bf16x8 el2 = ldfrag16(tb + 2560);
    f32x16 a;
    a = __builtin_amdgcn_mfma_f32_32x32x16_bf16(eh0, xh[0], zacc, 0, 0, 0);
    a = __builtin_amdgcn_mfma_f32_32x32x16_bf16(eh0, xl[0], a, 0, 0, 0);
    a = __builtin_amdgcn_mfma_f32_32x32x16_bf16(el0, xh[0], a, 0, 0, 0);
    a = __builtin_amdgcn_mfma_f32_32x32x16_bf16(eh1, xh[1], a, 0, 0, 0);
    a = __builtin_amdgcn_mfma_f32_32x32x16_bf16(eh1, xl[1], a, 0, 0, 0);
    a = __builtin_amdgcn_mfma_f32_32x32x16_bf16(el1, xh[1], a, 0, 0, 0);
    a = __builtin_amdgcn_mfma_f32_32x32x16_bf16(eh2, xh[2], a, 0, 0, 0);
    a = __builtin_amdgcn_mfma_f32_32x32x16_bf16(eh2, xl[2], a, 0, 0, 0);
    a = __builtin_amdgcn_mfma_f32_32x32x16_bf16(el2, xh[2], a, 0, 0, 0);

    // a[r] = 0.5*e2 - x.e for code tile*32 + 8*(r>>2) + 4*gg + (r&3)
#pragma unroll
    for (int q = 0; q < 4; ++q) {
      float gm = fminf(fminf(a[4 * q], a[4 * q + 1]), fminf(a[4 * q + 2], a[4 * q + 3]));
      if (gm < thr) {
#pragma unroll
        for (int j = 0; j < 4; ++j) {
          if (a[4 * q + j] < thr) {
            int c = tile * 32 + 8 * q + 4 * gg + j;
            // np-fp32-exact distance (serial ascending, unfused) — verified r6
            float dot = 0.f;
            const float* ef = etg + (size_t)c * KD;
#pragma unroll
            for (int k = 0; k < KD; ++k)
              dot = __fadd_rn(dot, __fmul_rn(x[k], ef[k]));
            float d = __fadd_rn(__fsub_rn(x2np, __fadd_rn(dot, dot)), e2g[c]);
            if (d < best_d) {
              best_d = d;
              best_i = c;
              thr = (best_d + EPS_D - x2np) * 0.5f;
            }
          }
        }
      }
    }
  }

  // merge the two k-half lanes of each row (index tiebreak = np first-min)
  {
    float od = __shfl_xor(best_d, 32);
    int oi = __shfl_xor(best_i, 32);
    if (od < best_d || (od == best_d && oi < best_i)) { best_d = od; best_i = oi; }
  }

  // ---- epilogue: STE write + loss partial, static k-halves per gg
  const float4* eb4 = (const float4*)(etg + (size_t)best_i * KD);
  float* op = out + (size_t)n * ZN + (size_t)g * ZG + tt;
  float ls = 0.f;
  if (gg == 0) {
#pragma unroll
    for (int p = 0; p < 5; ++p) {
      float4 v = eb4[p];
      int k = 4 * p;
      float d0 = __fsub_rn(v.x, x[k + 0]); ls = fmaf(d0, d0, ls); op[(size_t)(k + 0) * TP] = __fadd_rn(x[k + 0], d0);
      float d1 = __fsub_rn(v.y, x[k + 1]); ls = fmaf(d1, d1, ls); op[(size_t)(k + 1) * TP] = __fadd_rn(x[k + 1], d1);
      float d2 = __fsub_rn(v.z, x[k + 2]); ls = fmaf(d2, d2, ls); op[(size_t)(k + 2) * TP] = __fadd_rn(x[k + 2], d2);
      float d3 = __fsub_rn(v.w, x[k + 3]); ls = fmaf(d3, d3, ls); op[(size_t)(k + 3) * TP] = __fadd_rn(x[k + 3], d3);
    }
  } else {
#pragma unroll
    for (int p = 5; p < 10; ++p) {
      float4 v = eb4[p];
      int k = 4 * p;
      float d0 = __fsub_rn(v.x, x[k + 0]); ls = fmaf(d0, d0, ls); op[(size_t)(k + 0) * TP] = __fadd_rn(x[k + 0], d0);
      float d1 = __fsub_rn(v.y, x[k + 1]); ls = fmaf(d1, d1, ls); op[(size_t)(k + 1) * TP] = __fadd_rn(x[k + 1], d1);
      float d2 = __fsub_rn(v.z, x[k + 2]); ls = fmaf(d2, d2, ls); op[(size_t)(k + 2) * TP] = __fadd_rn(x[k + 2], d2);
      float d3 = __fsub_rn(v.w, x[k + 3]); ls = fmaf(d3, d3, ls); op[(size_t)(k + 3) * TP] = __fadd_rn(x[k + 3], d3);
    }
  }

  // ---- deterministic segmented block reduce (block straddles <=1 n boundary)
  const int n_lo = (bb * RPB) / TP;
  r0s[tid] = (n == n_lo) ? ls : 0.f;
  r1s[tid] = (n == n_lo) ? 0.f : ls;
  __syncthreads();
  for (int s = THREADS / 2; s > 0; s >>= 1) {
    if (tid < s) {
      r0s[tid] += r0s[tid + s];
      r1s[tid] += r1s[tid + s];
    }
    __syncthreads();
  }
  if (tid == 0) {
    partials[((size_t)g * NBLK + bb) * 2 + 0] = r0s[0];
    partials[((size_t)g * NBLK + bb) * 2 + 1] = r1s[0];
  }
}

// ---- final: fixed-order reduction of per-block partials -> vq_loss[n]
__global__ void loss_kernel(const float* __restrict__ partials,
                            float* __restrict__ vq) {
  int n = threadIdx.x;
  if (n >= NB) return;
  float acc = 0.f;
  for (int g = 0; g < NG; ++g) {
    float s = 0.f;
    int b0 = (n * TP) / RPB;
    int b1 = ((n + 1) * TP - 1) / RPB;
    for (int b = b0; b <= b1; ++b) {
      int n_lo = (b * RPB) / TP;
      s += partials[((size_t)g * NBLK + b) * 2 + ((n == n_lo) ? 0 : 1)];
    }
    acc += 0.25f * (s / 80000.0f);
  }
  vq[n] = acc / 6.0f;
}

extern "C" void kernel_launch(void* const* d_in, const int* in_sizes, int n_in,
                              void* d_out, int out_size, void* d_ws, size_t ws_size,
                              hipStream_t stream) {
  const float* z = (const float*)d_in[0];
  const float* emb = (const float*)d_in[1];
  float* out = (float*)d_out;

  float* et = (float*)d_ws;                          // 983,040 B
  float* e2 = et + (size_t)NG * CB * KD;             // 24,576 B
  float* partials = e2 + (size_t)NG * CB;            // 24,000 B
  unsigned short* epack = (unsigned short*)((char*)d_ws + 1031680);  // 1,179,648 B (16B aligned)

  prep_kernel<<<dim3(CB / 256, NG), 256, 0, stream>>>(emb, et, e2, epack);
  vq_kernel<<<dim3(NBLK, NG), THREADS, 0, stream>>>(z, et, e2, epack, out, partials);
  loss_kernel<<<1, 64, 0, stream>>>(partials, out + (size_t)NB * 60 * 8000);
}

// Round 11
// 289.772 us; speedup vs baseline: 2.2977x; 2.2977x over previous
//
#include <hip/hip_runtime.h>
#include <math.h>

#define NG 6
#define KD 40
#define CB 1024
#define NB 32
#define TP 2000
#define RPB 128              // rows per block (4 waves x 32, gg-paired)
#define THREADS 256
#define NBLK 500             // 64000 / 128
#define ZN 480000
#define ZG 80000
#define EPS_D 0.02f
#define PK_G 98304           // shorts per group in Epack (32 tiles * 3072)
#define PK_T 3072            // shorts per tile (hi 1536 + lo 1536)
#define PK_P 1536            // shorts per part
#define CHS 6144             // shorts per chunk (2 tiles)
#define NCH 16               // chunks of 2 tiles

typedef __attribute__((ext_vector_type(8))) short bf16x8;
typedef __attribute__((ext_vector_type(16))) float f32x16;

__device__ __forceinline__ unsigned short bf16rne(float v) {
  unsigned u = __float_as_uint(v);
  return (unsigned short)((u + 0x7FFFu + ((u >> 16) & 1u)) >> 16);
}
__device__ __forceinline__ float bf16val(unsigned short h) {
  return __uint_as_float(((unsigned)h) << 16);
}
__device__ __forceinline__ void bf16split(float v, unsigned short& h, unsigned short& l) {
  h = bf16rne(v);
  l = bf16rne(v - bf16val(h));
}
__device__ __forceinline__ bf16x8 ldfrag16(const unsigned short* p) {
  union { uint4 q; bf16x8 v; } u;
  u.q = *(const uint4*)p;
  return u.v;
}
__device__ __forceinline__ void gload_lds16(const void* g, void* l) {
  __builtin_amdgcn_global_load_lds(
      (const __attribute__((address_space(1))) unsigned int*)g,
      (__attribute__((address_space(3))) unsigned int*)l, 16, 0, 0);
}

// ---- prep: et[g][c][k] fp32; np-exact ||e||^2; fragment-ordered bf16 hi/lo pack
__global__ void prep_kernel(const float* __restrict__ emb, float* __restrict__ et,
                            float* __restrict__ e2, unsigned short* __restrict__ epack) {
  int c = blockIdx.x * blockDim.x + threadIdx.x;
  int g = blockIdx.y;
  if (c >= CB) return;
  const float* eg = emb + (size_t)g * KD * CB;
  float ev[KD];
  float* o = et + ((size_t)g * CB + c) * KD;
  float s = 0.f;
#pragma unroll
  for (int k = 0; k < KD; ++k) {
    float v = eg[k * CB + c];
    ev[k] = v;
    o[k] = v;
    s = __fadd_rn(s, __fmul_rn(v, v));   // np-exact serial unfused
  }
  e2[g * CB + c] = s;

  float sv = 0.5f * s;                    // 3-way bf16 split of the seed
  unsigned short p0 = bf16rne(sv);
  float v1 = sv - bf16val(p0);
  unsigned short p1 = bf16rne(v1);
  unsigned short p2 = bf16rne(v1 - bf16val(p1));

  int tile = c >> 5, j32 = c & 31;
  unsigned short* tb = epack + (size_t)g * PK_G + (size_t)tile * PK_T;
#pragma unroll
  for (int s2 = 0; s2 < 3; ++s2)
#pragma unroll
    for (int gg = 0; gg < 2; ++gg) {
      union { uint4 q; unsigned short sh[8]; } uh, ul;
#pragma unroll
      for (int j = 0; j < 8; ++j) {
        int k = s2 * 16 + gg * 8 + j;
        if (k < KD) {
          bf16split(ev[k], uh.sh[j], ul.sh[j]);
        } else {
          uh.sh[j] = (k == 40) ? p0 : (k == 41) ? p1 : (k == 42) ? p2 : (unsigned short)0;
          ul.sh[j] = 0;
        }
      }
      unsigned short* ph = tb + ((size_t)(s2 * 2 + gg) * 32 + j32) * 8;
      *(uint4*)ph = uh.q;
      *(uint4*)(ph + PK_P) = ul.q;
    }
}

__device__ __forceinline__ float npd_calc(const float* __restrict__ x,
                                          const float* __restrict__ ef,
                                          float e2c, float x2np) {
  float dot = 0.f;
#pragma unroll
  for (int k = 0; k < KD; ++k) dot = __fadd_rn(dot, __fmul_rn(x[k], ef[k]));
  return __fadd_rn(__fsub_rn(x2np, __fadd_rn(dot, dot)), e2c);
}

__global__ __launch_bounds__(THREADS, 4) void vq_kernel(
    const float* __restrict__ z, const float* __restrict__ et,
    const float* __restrict__ e2, const unsigned short* __restrict__ epack,
    float* __restrict__ out, float* __restrict__ partials) {
  const int g = blockIdx.y;
  const int bb = blockIdx.x;
  const int tid = threadIdx.x;
  const int lane = tid & 63;
  const int gg = lane >> 5;
  const int j32 = lane & 31;
  const int wid = tid >> 6;
  const int rowloc = wid * 32 + j32;
  const int rid = bb * RPB + rowloc;
  const int n = rid / TP;
  const int tt = rid - n * TP;

  const float* etg = et + (size_t)g * CB * KD;
  const float* e2g = e2 + g * CB;
  const unsigned short* egrp = epack + (size_t)g * PK_G;

  __shared__ __align__(16) unsigned short sbuf[2][CHS];
  __shared__ float r0s[THREADS], r1s[THREADS];

  // ---- stage chunk 0 immediately (DMA overlaps the x prologue)
#define STAGE(B, CH) { \
    const unsigned short* gsrc = egrp + (size_t)(CH) * CHS + wid * 512 + lane * 8; \
    unsigned short* lb = &sbuf[B][wid * 512]; \
    gload_lds16(gsrc, lb); \
    gload_lds16(gsrc + 2048, lb + 2048); \
    gload_lds16(gsrc + 4096, lb + 4096); }
  STAGE(0, 0)

  // ---- row x in registers; x2np (numpy pairwise-8, verified r6)
  const float* zp = z + (size_t)n * ZN + (size_t)g * ZG + tt;
  float x[KD];
#pragma unroll
  for (int k = 0; k < KD; ++k) x[k] = zp[(size_t)k * TP];
  float x2np;
  {
    float r[8];
#pragma unroll
    for (int j = 0; j < 8; ++j) r[j] = __fmul_rn(x[j], x[j]);
#pragma unroll
    for (int i = 8; i < KD; i += 8)
#pragma unroll
      for (int j = 0; j < 8; ++j)
        r[j] = __fadd_rn(r[j], __fmul_rn(x[i + j], x[i + j]));
    x2np = __fadd_rn(__fadd_rn(__fadd_rn(r[0], r[1]), __fadd_rn(r[2], r[3])),
                     __fadd_rn(__fadd_rn(r[4], r[5]), __fadd_rn(r[6], r[7])));
  }

  // ---- B fragments from -x, static per-gg k-slices (verified r9/r10)
  bf16x8 xh[3], xl[3];
#define PACK8(DH, DL, B0) { \
    union { unsigned short s[8]; bf16x8 v; } uh, ul; \
    _Pragma("unroll") \
    for (int j = 0; j < 8; ++j) { \
      unsigned short h, l; bf16split(-x[(B0) + j], h, l); \
      uh.s[j] = h; ul.s[j] = l; } \
    DH = uh.v; DL = ul.v; }
  if (gg == 0) {
    PACK8(xh[0], xl[0], 0)
    PACK8(xh[1], xl[1], 16)
    PACK8(xh[2], xl[2], 32)
  } else {
    PACK8(xh[0], xl[0], 8)
    PACK8(xh[1], xl[1], 24)
    union { unsigned short s[8]; bf16x8 v; } uh;
#pragma unroll
    for (int j = 0; j < 8; ++j) uh.s[j] = (j < 3) ? (unsigned short)0x3F80 : (unsigned short)0;
    xh[2] = uh.v;
    union { unsigned short s[8]; bf16x8 v; } uz;
#pragma unroll
    for (int j = 0; j < 8; ++j) uz.s[j] = 0;
    xl[2] = uz.v;
  }
#undef PACK8

  f32x16 zacc;
#pragma unroll
  for (int i = 0; i < 16; ++i) zacc[i] = 0.f;

  float thr = -INFINITY;   // seeded at tile 0; sc < thr <=> 2sc + x2 < best_d + EPS
  float best_d = INFINITY;
  int best_i = CB;

#define UPDATE(DV, CV) { \
    bool bt = (DV) < best_d || ((DV) == best_d && (CV) < best_i); \
    if (bt) { best_d = (DV); best_i = (CV); thr = (best_d + EPS_D - x2np) * 0.5f; } }

#define MASKPROC(TILE) { \
    unsigned msk = 0; \
    _Pragma("unroll") \
    for (int i = 0; i < 16; ++i) msk |= (a[i] < thr) ? (1u << i) : 0u; \
    while (msk) { \
      int i = __ffs(msk) - 1; \
      msk &= msk - 1; \
      int c = (TILE) * 32 + 8 * (i >> 2) + 4 * gg + (i & 3); \
      float dd = npd_calc(x, etg + (size_t)c * KD, e2g[c], x2np); \
      UPDATE(dd, c) \
    } }

#define COMPUTE_TILE(T2, TILE, SEED) { \
    const unsigned short* tb = &sbuf[cur][(T2) * PK_T + lane * 8]; \
    bf16x8 eh0 = ldfrag16(tb); \
    bf16x8 eh1 = ldfrag16(tb + 512); \
    bf16x8 eh2 = ldfrag16(tb + 1024); \
    bf16x8 el0 = ldfrag16(tb + 1536); \
    bf16x8 el1 = ldfrag16(tb + 2048); \
    bf16x8 el2 = ldfrag16(tb + 2560); \
    f32x16 a; \
    a = __builtin_amdgcn_mfma_f32_32x32x16_bf16(eh0, xh[0], zacc, 0, 0, 0); \
    a = __builtin_amdgcn_mfma_f32_32x32x16_bf16(eh0, xl[0], a, 0, 0, 0); \
    a = __builtin_amdgcn_mfma_f32_32x32x16_bf16(el0, xh[0], a, 0, 0, 0); \
    a = __builtin_amdgcn_mfma_f32_32x32x16_bf16(eh1, xh[1], a, 0, 0, 0); \
    a = __builtin_amdgcn_mfma_f32_32x32x16_bf16(eh1, xl[1], a, 0, 0, 0); \
    a = __builtin_amdgcn_mfma_f32_32x32x16_bf16(el1, xh[1], a, 0, 0, 0); \
    a = __builtin_amdgcn_mfma_f32_32x32x16_bf16(eh2, xh[2], a, 0, 0, 0); \
    a = __builtin_amdgcn_mfma_f32_32x32x16_bf16(eh2, xl[2], a, 0, 0, 0); \
    a = __builtin_amdgcn_mfma_f32_32x32x16_bf16(el2, xh[2], a, 0, 0, 0); \
    if (SEED) { \
      float m = a[0]; int mi = 0; \
      _Pragma("unroll") \
      for (int i = 1; i < 16; ++i) { if (a[i] < m) { m = a[i]; mi = i; } } \
      int c0 = 8 * (mi >> 2) + 4 * gg + (mi & 3); \
      float d0 = npd_calc(x, etg + (size_t)c0 * KD, e2g[c0], x2np); \
      UPDATE(d0, c0) \
    } \
    MASKPROC(TILE) }

  int cur = 0;
#pragma unroll 1
  for (int ch = 0; ch < NCH; ++ch) {
    if (ch + 1 < NCH) {
      STAGE(cur ^ 1, ch + 1)
      asm volatile("s_waitcnt vmcnt(3)" ::: "memory");  // chunk ch's 3 DMAs done; next 3 in flight
    } else {
      asm volatile("s_waitcnt vmcnt(0)" ::: "memory");
    }
    __builtin_amdgcn_s_barrier();
    COMPUTE_TILE(0, ch * 2, ch == 0)
    COMPUTE_TILE(1, ch * 2 + 1, false)
    __builtin_amdgcn_s_barrier();   // all waves done reading before next overwrite
    cur ^= 1;
  }

  // merge the two k-half lanes of each row ((d,c) ordering, np first-min)
  {
    float od = __shfl_xor(best_d, 32);
    int oi = __shfl_xor(best_i, 32);
    if (od < best_d || (od == best_d && oi < best_i)) { best_d = od; best_i = oi; }
  }

  // ---- epilogue: STE write + loss partial, static k-halves per gg
  const float4* eb4 = (const float4*)(etg + (size_t)best_i * KD);
  float* op = out + (size_t)n * ZN + (size_t)g * ZG + tt;
  float ls = 0.f;
  if (gg == 0) {
#pragma unroll
    for (int p = 0; p < 5; ++p) {
      float4 v = eb4[p];
      int k = 4 * p;
      float d0 = __fsub_rn(v.x, x[k + 0]); ls = fmaf(d0, d0, ls); op[(size_t)(k + 0) * TP] = __fadd_rn(x[k + 0], d0);
      float d1 = __fsub_rn(v.y, x[k + 1]); ls = fmaf(d1, d1, ls); op[(size_t)(k + 1) * TP] = __fadd_rn(x[k + 1], d1);
      float d2 = __fsub_rn(v.z, x[k + 2]); ls = fmaf(d2, d2, ls); op[(size_t)(k + 2) * TP] = __fadd_rn(x[k + 2], d2);
      float d3 = __fsub_rn(v.w, x[k + 3]); ls = fmaf(d3, d3, ls); op[(size_t)(k + 3) * TP] = __fadd_rn(x[k + 3], d3);
    }
  } else {
#pragma unroll
    for (int p = 5; p < 10; ++p) {
      float4 v = eb4[p];
      int k = 4 * p;
      float d0 = __fsub_rn(v.x, x[k + 0]); ls = fmaf(d0, d0, ls); op[(size_t)(k + 0) * TP] = __fadd_rn(x[k + 0], d0);
      float d1 = __fsub_rn(v.y, x[k + 1]); ls = fmaf(d1, d1, ls); op[(size_t)(k + 1) * TP] = __fadd_rn(x[k + 1], d1);
      float d2 = __fsub_rn(v.z, x[k + 2]); ls = fmaf(d2, d2, ls); op[(size_t)(k + 2) * TP] = __fadd_rn(x[k + 2], d2);
      float d3 = __fsub_rn(v.w, x[k + 3]); ls = fmaf(d3, d3, ls); op[(size_t)(k + 3) * TP] = __fadd_rn(x[k + 3], d3);
    }
  }

  // ---- deterministic segmented block reduce (block straddles <=1 n boundary)
  const int n_lo = (bb * RPB) / TP;
  r0s[tid] = (n == n_lo) ? ls : 0.f;
  r1s[tid] = (n == n_lo) ? 0.f : ls;
  __syncthreads();
  for (int s = THREADS / 2; s > 0; s >>= 1) {
    if (tid < s) {
      r0s[tid] += r0s[tid + s];
      r1s[tid] += r1s[tid + s];
    }
    __syncthreads();
  }
  if (tid == 0) {
    partials[((size_t)g * NBLK + bb) * 2 + 0] = r0s[0];
    partials[((size_t)g * NBLK + bb) * 2 + 1] = r1s[0];
  }
}

// ---- final: fixed-order reduction of per-block partials -> vq_loss[n]
__global__ void loss_kernel(const float* __restrict__ partials,
                            float* __restrict__ vq) {
  int n = threadIdx.x;
  if (n >= NB) return;
  float acc = 0.f;
  for (int g = 0; g < NG; ++g) {
    float s = 0.f;
    int b0 = (n * TP) / RPB;
    int b1 = ((n + 1) * TP - 1) / RPB;
    for (int b = b0; b <= b1; ++b) {
      int n_lo = (b * RPB) / TP;
      s += partials[((size_t)g * NBLK + b) * 2 + ((n == n_lo) ? 0 : 1)];
    }
    acc += 0.25f * (s / 80000.0f);
  }
  vq[n] = acc / 6.0f;
}

extern "C" void kernel_launch(void* const* d_in, const int* in_sizes, int n_in,
                              void* d_out, int out_size, void* d_ws, size_t ws_size,
                              hipStream_t stream) {
  const float* z = (const float*)d_in[0];
  const float* emb = (const float*)d_in[1];
  float* out = (float*)d_out;

  float* et = (float*)d_ws;                          // 983,040 B
  float* e2 = et + (size_t)NG * CB * KD;             // 24,576 B
  float* partials = e2 + (size_t)NG * CB;            // 24,000 B
  unsigned short* epack = (unsigned short*)((char*)d_ws + 1031680);  // 1,179,648 B

  prep_kernel<<<dim3(CB / 256, NG), 256, 0, stream>>>(emb, et, e2, epack);
  vq_kernel<<<dim3(NBLK, NG), THREADS, 0, stream>>>(z, et, e2, epack, out, partials);
  loss_kernel<<<1, 64, 0, stream>>>(partials, out + (size_t)NB * 60 * 8000);
}